// Round 4
// baseline (1121.162 us; speedup 1.0000x reference)
//
#include <hip/hip_runtime.h>

#define NN 131072   // nodes
#define NE 262144   // edges
#define NG 4096     // graphs
#define EMBD 256

typedef unsigned short bfu;  // raw bf16 bits (storage only; all compute f32)

__device__ __forceinline__ float bf2f(bfu u) {
  return __uint_as_float(((unsigned)u) << 16);
}
__device__ __forceinline__ bfu f2bf(float f) {  // round-to-nearest-even
  unsigned u = __float_as_uint(f);
  u += 0x7FFF + ((u >> 16) & 1);
  return (bfu)(u >> 16);
}
__device__ __forceinline__ float4 ld4(const float* p) {
  return *reinterpret_cast<const float4*>(p);
}
__device__ __forceinline__ float4 ld4(const bfu* p) {
  ushort4 u = *reinterpret_cast<const ushort4*>(p);
  return make_float4(bf2f(u.x), bf2f(u.y), bf2f(u.z), bf2f(u.w));
}
__device__ __forceinline__ void st4(float* p, float4 v) {
  *reinterpret_cast<float4*>(p) = v;
}
__device__ __forceinline__ void st4(bfu* p, float4 v) {
  *reinterpret_cast<ushort4*>(p) =
      make_ushort4(f2bf(v.x), f2bf(v.y), f2bf(v.z), f2bf(v.w));
}

// ---------------------------------------------------------------------------
__global__ __launch_bounds__(256) void k_zero(float4* p, int n4) {
  for (int i = blockIdx.x * 256 + threadIdx.x; i < n4; i += gridDim.x * 256)
    p[i] = make_float4(0.f, 0.f, 0.f, 0.f);
}

// ---------------------------------------------------------------------------
// Atom encoder: h[n][c] = sum_f atom_emb[x[n][f] + off[f]][c]. Wave = node,
// so the 9 x-reads are wave-uniform; emb table 176 KB -> L2-hot.
template <typename TH>
__global__ __launch_bounds__(256) void k_atom_encode(
    const float* __restrict__ atom_emb, const int* __restrict__ x,
    TH* __restrict__ h) {
  const int idx = blockIdx.x * 256 + threadIdx.x;
  const int n = idx >> 6;
  const int c = (idx & 63) << 2;
  const int off[9] = {0, 119, 123, 135, 147, 157, 163, 168, 170};
  const int* xr = x + n * 9;
  float4 acc = make_float4(0.f, 0.f, 0.f, 0.f);
#pragma unroll
  for (int f = 0; f < 9; ++f) {
    const float4 v =
        *reinterpret_cast<const float4*>(atom_emb + (xr[f] + off[f]) * EMBD + c);
    acc.x += v.x; acc.y += v.y; acc.z += v.z; acc.w += v.w;
  }
  st4(h + (size_t)n * EMBD + c, acc);
}

// ---------------------------------------------------------------------------
// CSR build over destinations + source-degree count.
__global__ __launch_bounds__(256) void k_count(const int* __restrict__ ei,
                                               float* __restrict__ deg,
                                               int* __restrict__ bcnt) {
  const int e = blockIdx.x * 256 + threadIdx.x;
  if (e >= NE) return;
  atomicAdd(&deg[ei[e]], 1.0f);
  atomicAdd(&bcnt[ei[NE + e]], 1);
}

__global__ __launch_bounds__(256) void k_bsum(const int* __restrict__ bcnt,
                                              int* __restrict__ bsum) {
  __shared__ int s[256];
  const int t = threadIdx.x;
  s[t] = bcnt[blockIdx.x * 256 + t];
  __syncthreads();
  for (int o = 128; o; o >>= 1) {
    if (t < o) s[t] += s[t + o];
    __syncthreads();
  }
  if (t == 0) bsum[blockIdx.x] = s[0];
}

__global__ __launch_bounds__(512) void k_bscan(int* __restrict__ bsum) {
  __shared__ int s[512];
  const int t = threadIdx.x;
  s[t] = bsum[t];
  __syncthreads();
  for (int o = 1; o < 512; o <<= 1) {
    const int v = (t >= o) ? s[t - o] : 0;
    __syncthreads();
    s[t] += v;
    __syncthreads();
  }
  bsum[t] = t ? s[t - 1] : 0;  // exclusive
}

__global__ __launch_bounds__(256) void k_rowptr(const int* __restrict__ bcnt,
                                                const int* __restrict__ bsum,
                                                int* __restrict__ rowptr) {
  __shared__ int s[256];
  const int t = threadIdx.x;
  const int n = blockIdx.x * 256 + t;
  s[t] = bcnt[n];
  __syncthreads();
  for (int o = 1; o < 256; o <<= 1) {
    const int v = (t >= o) ? s[t - o] : 0;
    __syncthreads();
    s[t] += v;
    __syncthreads();
  }
  rowptr[n] = bsum[blockIdx.x] + (t ? s[t - 1] : 0);
}

__global__ __launch_bounds__(256) void k_scatter(const int* __restrict__ ei,
                                                 const int* __restrict__ rowptr,
                                                 int* __restrict__ ticket,
                                                 int* __restrict__ eids) {
  const int e = blockIdx.x * 256 + threadIdx.x;
  if (e >= NE) return;
  const int col = ei[NE + e];
  const int slot = atomicAdd(&ticket[col], 1);
  eids[rowptr[col] + slot] = e;
}

__global__ __launch_bounds__(256) void k_finish_deg(float* __restrict__ deg,
                                                    float* __restrict__ dinv) {
  const int n = blockIdx.x * 256 + threadIdx.x;
  const float d = deg[n] + 1.0f;
  deg[n] = d;
  dinv[n] = 1.0f / sqrtf(d);
}

// ---------------------------------------------------------------------------
// GEMM: C[M,256] = A[M,256] @ W[256,256] + bias (f32 vector ALU; no fp32 MFMA)
// 128x128 tile, BK=16, 256 threads, 8x8 micro-tile.
#define BM 128
#define BN 128
#define BK 16
template <typename TH, typename TL>
__global__ __launch_bounds__(256) void k_gemm_bias(
    const TH* __restrict__ A, const float* __restrict__ W,
    const float* __restrict__ bias, TL* __restrict__ C) {
  __shared__ float As[BK][BM];  // transposed A tile
  __shared__ float Bs[BK][BN];
  const int t = threadIdx.x;
  const int tx = t & 15, ty = t >> 4;
  const int bm = blockIdx.x * BM;
  const int bn = blockIdx.y * BN;

  float acc[8][8];
#pragma unroll
  for (int i = 0; i < 8; ++i)
#pragma unroll
    for (int j = 0; j < 8; ++j) acc[i][j] = 0.f;

  const int arow = t >> 2, aseg = t & 3;
  const int bk_ = t >> 5, bseg = t & 31;

  for (int kb = 0; kb < 256; kb += BK) {
#pragma unroll
    for (int i = 0; i < 2; ++i) {
      const int row = arow + i * 64;
      const float4 v = ld4(A + (size_t)(bm + row) * EMBD + kb + aseg * 4);
      As[aseg * 4 + 0][row] = v.x;
      As[aseg * 4 + 1][row] = v.y;
      As[aseg * 4 + 2][row] = v.z;
      As[aseg * 4 + 3][row] = v.w;
    }
#pragma unroll
    for (int i = 0; i < 2; ++i) {
      const int kk = bk_ + i * 8;
      *reinterpret_cast<float4*>(&Bs[kk][bseg * 4]) =
          *reinterpret_cast<const float4*>(W + (kb + kk) * EMBD + bn + bseg * 4);
    }
    __syncthreads();
#pragma unroll
    for (int k = 0; k < BK; ++k) {
      float a[8], b[8];
      *reinterpret_cast<float4*>(&a[0]) =
          *reinterpret_cast<const float4*>(&As[k][ty * 4]);
      *reinterpret_cast<float4*>(&a[4]) =
          *reinterpret_cast<const float4*>(&As[k][64 + ty * 4]);
      *reinterpret_cast<float4*>(&b[0]) =
          *reinterpret_cast<const float4*>(&Bs[k][tx * 4]);
      *reinterpret_cast<float4*>(&b[4]) =
          *reinterpret_cast<const float4*>(&Bs[k][64 + tx * 4]);
#pragma unroll
      for (int i = 0; i < 8; ++i)
#pragma unroll
        for (int j = 0; j < 8; ++j) acc[i][j] = fmaf(a[i], b[j], acc[i][j]);
    }
    __syncthreads();
  }

  float bl[8];
#pragma unroll
  for (int j = 0; j < 4; ++j) {
    bl[j] = bias[bn + tx * 4 + j];
    bl[4 + j] = bias[bn + 64 + tx * 4 + j];
  }
#pragma unroll
  for (int i = 0; i < 8; ++i) {
    const int r = bm + ((i < 4) ? (ty * 4 + i) : (64 + ty * 4 + i - 4));
    st4(C + (size_t)r * EMBD + bn + tx * 4,
        make_float4(acc[i][0] + bl[0], acc[i][1] + bl[1], acc[i][2] + bl[2],
                    acc[i][3] + bl[3]));
    st4(C + (size_t)r * EMBD + bn + 64 + tx * 4,
        make_float4(acc[i][4] + bl[4], acc[i][5] + bl[5], acc[i][6] + bl[6],
                    acc[i][7] + bl[7]));
  }
}

// ---------------------------------------------------------------------------
// Fused gather + update, wave per node, CSR in-edges, accumulators in regs.
// No atomics, no agg buffer. Per-edge control loads are wave-uniform.
template <typename TL, typename TH>
__global__ __launch_bounds__(256) void k_gather_update(
    const int* __restrict__ ei, const int* __restrict__ ea,
    const float* __restrict__ dinv, const float* __restrict__ bond,
    const TL* __restrict__ hl, const float* __restrict__ deg,
    const int* __restrict__ bcnt, const int* __restrict__ rowptr,
    const int* __restrict__ eids, const float* __restrict__ root,
    const float* __restrict__ gamma, const float* __restrict__ beta,
    const float* __restrict__ mean, const float* __restrict__ var,
    TH* __restrict__ out, const int do_relu) {
  const int idx = blockIdx.x * 256 + threadIdx.x;
  const int n = idx >> 6;
  const int c = (idx & 63) << 2;
  const int base = rowptr[n];
  const int cnt = bcnt[n];
  const float dn = dinv[n];

  float a0 = 0.f, a1 = 0.f, a2 = 0.f, a3 = 0.f;
  for (int s = 0; s < cnt; ++s) {
    const int e = eids[base + s];
    const int row = ei[e];
    const float nm = dinv[row] * dn;
    const int i0 = ea[e * 3 + 0];
    const int i1 = ea[e * 3 + 1] + 5;
    const int i2 = ea[e * 3 + 2] + 11;
    const float4 b0 = *reinterpret_cast<const float4*>(bond + i0 * EMBD + c);
    const float4 b1 = *reinterpret_cast<const float4*>(bond + i1 * EMBD + c);
    const float4 b2 = *reinterpret_cast<const float4*>(bond + i2 * EMBD + c);
    const float4 hv = ld4(hl + (size_t)row * EMBD + c);
    a0 += nm * fmaxf(hv.x + b0.x + b1.x + b2.x, 0.f);
    a1 += nm * fmaxf(hv.y + b0.y + b1.y + b2.y, 0.f);
    a2 += nm * fmaxf(hv.z + b0.z + b1.z + b2.z, 0.f);
    a3 += nm * fmaxf(hv.w + b0.w + b1.w + b2.w, 0.f);
  }

  const float di = 1.0f / deg[n];
  const float4 hv = ld4(hl + (size_t)n * EMBD + c);
  const float4 r = *reinterpret_cast<const float4*>(root + c);
  const float4 mn = *reinterpret_cast<const float4*>(mean + c);
  const float4 g = *reinterpret_cast<const float4*>(gamma + c);
  const float4 vv = *reinterpret_cast<const float4*>(var + c);
  const float4 bt = *reinterpret_cast<const float4*>(beta + c);
  float v0 = a0 + fmaxf(hv.x + r.x, 0.f) * di;
  float v1 = a1 + fmaxf(hv.y + r.y, 0.f) * di;
  float v2 = a2 + fmaxf(hv.z + r.z, 0.f) * di;
  float v3 = a3 + fmaxf(hv.w + r.w, 0.f) * di;
  v0 = (v0 - mn.x) * (g.x / sqrtf(vv.x + 1e-5f)) + bt.x;
  v1 = (v1 - mn.y) * (g.y / sqrtf(vv.y + 1e-5f)) + bt.y;
  v2 = (v2 - mn.z) * (g.z / sqrtf(vv.z + 1e-5f)) + bt.z;
  v3 = (v3 - mn.w) * (g.w / sqrtf(vv.w + 1e-5f)) + bt.w;
  if (do_relu) {
    v0 = fmaxf(v0, 0.f); v1 = fmaxf(v1, 0.f);
    v2 = fmaxf(v2, 0.f); v3 = fmaxf(v3, 0.f);
  }
  st4(out + (size_t)n * EMBD + c, make_float4(v0, v1, v2, v3));
}

// ---------------------------------------------------------------------------
// Pool: batch sorted -> run-length accumulate, one atomic per (run, channel).
// Thread c reads channel c of 128 consecutive nodes: coalesced across block.
template <typename TH>
__global__ __launch_bounds__(256) void k_pool(const TH* __restrict__ h,
                                              const int* __restrict__ batch,
                                              float* __restrict__ out) {
  const int c = threadIdx.x;
  const int n0 = blockIdx.x * 128;
  float acc = 0.f;
  int gprev = batch[n0];
  for (int i = 0; i < 128; ++i) {
    const int n = n0 + i;
    const int g = batch[n];
    if (g != gprev) {
      atomicAdd(&out[gprev * EMBD + c], acc);
      acc = 0.f;
      gprev = g;
    }
    acc += (sizeof(TH) == 4) ? ((const float*)h)[(size_t)n * EMBD + c]
                             : bf2f(((const bfu*)h)[(size_t)n * EMBD + c]);
  }
  atomicAdd(&out[gprev * EMBD + c], acc);
}

// ---------------------------------------------------------------------------
template <typename TH, typename TL>
static void run_pipeline(const float* atom_emb, const float* bond_emb,
                         const float* W, const float* b, const float* root,
                         const float* gamma, const float* beta,
                         const float* mean, const float* var, const int* x,
                         const int* ei, const int* ea, const int* batch,
                         float* out, TH* X, TL* Y, hipStream_t stream) {
  // graph metadata lives in d_out (4 MiB) until the final pool; peak use
  // 5*NN + 512 + NE ints = 3.50 MiB <= out_size.
  float* deg = out;                      // NN f32
  float* dnv = out + NN;                 // NN f32
  int* bcnt = (int*)(out + 2 * NN);      // NN
  int* rowptr = bcnt + NN;               // NN
  int* ticket = rowptr + NN;             // NN
  int* bsum = ticket + NN;               // 512
  int* eids = bsum + 512;                // NE

  // zero deg/dnv/bcnt/rowptr/ticket/bsum in one pass
  k_zero<<<1024, 256, 0, stream>>>((float4*)out, (5 * NN + 512) / 4);
  k_atom_encode<TH><<<NN / 4, 256, 0, stream>>>(atom_emb, x, X);
  k_count<<<NE / 256, 256, 0, stream>>>(ei, deg, bcnt);
  k_bsum<<<NN / 256, 256, 0, stream>>>(bcnt, bsum);
  k_bscan<<<1, 512, 0, stream>>>(bsum);
  k_rowptr<<<NN / 256, 256, 0, stream>>>(bcnt, bsum, rowptr);
  k_scatter<<<NE / 256, 256, 0, stream>>>(ei, rowptr, ticket, eids);
  k_finish_deg<<<NN / 256, 256, 0, stream>>>(deg, dnv);

  for (int l = 0; l < 3; ++l) {
    k_gemm_bias<TH, TL><<<dim3(NN / BM, EMBD / BN), 256, 0, stream>>>(
        X, W + l * EMBD * EMBD, b + l * EMBD, Y);
    k_gather_update<TL, TH><<<NN / 4, 256, 0, stream>>>(
        ei, ea, dnv, bond_emb + l * 13 * EMBD, Y, deg, bcnt, rowptr, eids,
        root + l * EMBD, gamma + l * EMBD, beta + l * EMBD, mean + l * EMBD,
        var + l * EMBD, X, (l < 2) ? 1 : 0);
  }
  // metadata now dead: zero the full output, then pool h3 (in X) into it
  k_zero<<<1024, 256, 0, stream>>>((float4*)out, NG * EMBD / 4);
  k_pool<TH><<<NN / 128, 256, 0, stream>>>(X, batch, out);
}

extern "C" void kernel_launch(void* const* d_in, const int* in_sizes, int n_in,
                              void* d_out, int out_size, void* d_ws,
                              size_t ws_size, hipStream_t stream) {
  const float* atom_emb = (const float*)d_in[0];
  const float* bond_emb = (const float*)d_in[1];
  const float* W = (const float*)d_in[2];
  const float* b = (const float*)d_in[3];
  const float* root = (const float*)d_in[4];
  const float* gamma = (const float*)d_in[5];
  const float* beta = (const float*)d_in[6];
  const float* mean = (const float*)d_in[7];
  const float* var = (const float*)d_in[8];
  const int* x = (const int*)d_in[9];
  const int* ei = (const int*)d_in[10];
  const int* ea = (const int*)d_in[11];
  const int* batch = (const int*)d_in[12];
  float* out = (float*)d_out;

  const size_t H = (size_t)NN * EMBD;  // elements per h buffer
  char* ws = (char*)d_ws;

  if (ws_size >= 2 * H * sizeof(float)) {
    // Tier A: full f32 (needs exactly 256 MiB of ws)
    float* X = (float*)ws;
    float* Y = X + H;
    run_pipeline<float, float>(atom_emb, bond_emb, W, b, root, gamma, beta,
                               mean, var, x, ei, ea, batch, out, X, Y, stream);
  } else if (ws_size >= H * sizeof(bfu) + H * sizeof(float)) {
    // Tier B: bf16 h storage, f32 hl (192 MiB)
    bfu* X = (bfu*)ws;
    float* Y = (float*)(ws + H * sizeof(bfu));
    run_pipeline<bfu, float>(atom_emb, bond_emb, W, b, root, gamma, beta,
                             mean, var, x, ei, ea, batch, out, X, Y, stream);
  } else if (ws_size >= 2 * H * sizeof(bfu)) {
    // Tier C: bf16 both (exactly 128 MiB)
    bfu* X = (bfu*)ws;
    bfu* Y = X + H;
    run_pipeline<bfu, bfu>(atom_emb, bond_emb, W, b, root, gamma, beta, mean,
                           var, x, ei, ea, batch, out, X, Y, stream);
  } else {
    // ws too small for any layout: emit zeros (fails validation cleanly,
    // distinguishing "ws too small" from a memory fault)
    k_zero<<<1024, 256, 0, stream>>>((float4*)out, NG * EMBD / 4);
  }
}

// Round 7
// 747.520 us; speedup vs baseline: 1.4998x; 1.4998x over previous
//
#include <hip/hip_runtime.h>

#define NN 131072   // nodes
#define NE 262144   // edges
#define NG 4096     // graphs
#define EMBD 256

typedef unsigned short bfu;  // raw bf16 bits (storage only; compute f32)
typedef __attribute__((ext_vector_type(8))) short short8v;   // MFMA A/B frag
typedef __attribute__((ext_vector_type(4))) float f32x4;     // MFMA C/D frag

__device__ __forceinline__ float bf2f(bfu u) {
  return __uint_as_float(((unsigned)u) << 16);
}
__device__ __forceinline__ bfu f2bf(float f) {  // round-to-nearest-even
  unsigned u = __float_as_uint(f);
  u += 0x7FFF + ((u >> 16) & 1);
  return (bfu)(u >> 16);
}
__device__ __forceinline__ float4 ld4(const float* p) {
  return *reinterpret_cast<const float4*>(p);
}
__device__ __forceinline__ float4 ld4(const bfu* p) {
  ushort4 u = *reinterpret_cast<const ushort4*>(p);
  return make_float4(bf2f(u.x), bf2f(u.y), bf2f(u.z), bf2f(u.w));
}
__device__ __forceinline__ void st4(float* p, float4 v) {
  *reinterpret_cast<float4*>(p) = v;
}
__device__ __forceinline__ void st4(bfu* p, float4 v) {
  *reinterpret_cast<ushort4*>(p) =
      make_ushort4(f2bf(v.x), f2bf(v.y), f2bf(v.z), f2bf(v.w));
}
__device__ __forceinline__ void st1(float* p, float v) { *p = v; }
__device__ __forceinline__ void st1(bfu* p, float v) { *p = f2bf(v); }

// ---------------------------------------------------------------------------
__global__ __launch_bounds__(256) void k_zero(float4* p, int n4) {
  for (int i = blockIdx.x * 256 + threadIdx.x; i < n4; i += gridDim.x * 256)
    p[i] = make_float4(0.f, 0.f, 0.f, 0.f);
}

// ---------------------------------------------------------------------------
// Atom encoder: h[n][c] = sum_f atom_emb[x[n][f] + off[f]][c]. Wave = node.
__global__ __launch_bounds__(256) void k_atom_encode(
    const float* __restrict__ atom_emb, const int* __restrict__ x,
    bfu* __restrict__ h) {
  const int idx = blockIdx.x * 256 + threadIdx.x;
  const int n = idx >> 6;
  const int c = (idx & 63) << 2;
  const int off[9] = {0, 119, 123, 135, 147, 157, 163, 168, 170};
  const int* xr = x + n * 9;
  float4 acc = make_float4(0.f, 0.f, 0.f, 0.f);
#pragma unroll
  for (int f = 0; f < 9; ++f) {
    const float4 v =
        *reinterpret_cast<const float4*>(atom_emb + (xr[f] + off[f]) * EMBD + c);
    acc.x += v.x; acc.y += v.y; acc.z += v.z; acc.w += v.w;
  }
  st4(h + (size_t)n * EMBD + c, acc);
}

// ---------------------------------------------------------------------------
// CSR build over destinations + source-degree count.
__global__ __launch_bounds__(256) void k_count(const int* __restrict__ ei,
                                               float* __restrict__ deg,
                                               int* __restrict__ bcnt) {
  const int e = blockIdx.x * 256 + threadIdx.x;
  if (e >= NE) return;
  atomicAdd(&deg[ei[e]], 1.0f);
  atomicAdd(&bcnt[ei[NE + e]], 1);
}

__global__ __launch_bounds__(256) void k_bsum(const int* __restrict__ bcnt,
                                              int* __restrict__ bsum) {
  __shared__ int s[256];
  const int t = threadIdx.x;
  s[t] = bcnt[blockIdx.x * 256 + t];
  __syncthreads();
  for (int o = 128; o; o >>= 1) {
    if (t < o) s[t] += s[t + o];
    __syncthreads();
  }
  if (t == 0) bsum[blockIdx.x] = s[0];
}

__global__ __launch_bounds__(512) void k_bscan(int* __restrict__ bsum) {
  __shared__ int s[512];
  const int t = threadIdx.x;
  s[t] = bsum[t];
  __syncthreads();
  for (int o = 1; o < 512; o <<= 1) {
    const int v = (t >= o) ? s[t - o] : 0;
    __syncthreads();
    s[t] += v;
    __syncthreads();
  }
  bsum[t] = t ? s[t - 1] : 0;  // exclusive
}

__global__ __launch_bounds__(256) void k_rowptr(const int* __restrict__ bcnt,
                                                const int* __restrict__ bsum,
                                                int* __restrict__ rowptr) {
  __shared__ int s[256];
  const int t = threadIdx.x;
  const int n = blockIdx.x * 256 + t;
  s[t] = bcnt[n];
  __syncthreads();
  for (int o = 1; o < 256; o <<= 1) {
    const int v = (t >= o) ? s[t - o] : 0;
    __syncthreads();
    s[t] += v;
    __syncthreads();
  }
  rowptr[n] = bsum[blockIdx.x] + (t ? s[t - 1] : 0);
}

__global__ __launch_bounds__(256) void k_scatter(const int* __restrict__ ei,
                                                 const int* __restrict__ rowptr,
                                                 int* __restrict__ ticket,
                                                 int* __restrict__ eids) {
  const int e = blockIdx.x * 256 + threadIdx.x;
  if (e >= NE) return;
  const int col = ei[NE + e];
  const int slot = atomicAdd(&ticket[col], 1);
  eids[rowptr[col] + slot] = e;
}

__global__ __launch_bounds__(256) void k_finish_deg(float* __restrict__ deg,
                                                    float* __restrict__ dinv) {
  const int n = blockIdx.x * 256 + threadIdx.x;
  const float d = deg[n] + 1.0f;
  deg[n] = d;
  dinv[n] = 1.0f / sqrtf(d);
}

// ---------------------------------------------------------------------------
// W split-transpose: Whi[l][n][k] = bf16(W[l][k][n]); Wlo = bf16(residual).
// Whi+Wlo represents W to ~2^-17 rel: GEMM precision == f32-W with bf16-A.
__global__ __launch_bounds__(256) void k_wt(const float* __restrict__ W,
                                            bfu* __restrict__ Whi,
                                            bfu* __restrict__ Wlo) {
  const int idx = blockIdx.x * 256 + threadIdx.x;  // (l,k,n), n fastest
  if (idx >= 3 * 256 * 256) return;
  const int n = idx & 255;
  const int k = (idx >> 8) & 255;
  const int l = idx >> 16;
  const float w = W[idx];
  const bfu hi = f2bf(w);
  const bfu lo = f2bf(w - bf2f(hi));
  const int o = ((l * 256 + n) << 8) + k;
  Whi[o] = hi;
  Wlo[o] = lo;
}

// ---------------------------------------------------------------------------
// bf16 MFMA GEMM: C[M,256] = A[M,256] @ W + bias, W = Whi + Wlo (split bf16).
// Block: 64 rows x all 256 cols, 4 waves (wave w owns cols [64w,64w+64)).
// A staged once to LDS via global_load_lds (inverse-swizzled source, rule 21);
// ds_read_b128 with byte ^= (row&7)<<4 kills the stride-512 bank conflict.
// B frags read straight from L2-hot Whi/Wlo (768 KB). No K-loop barriers.
template <typename TL>
__global__ __launch_bounds__(256) void k_gemm_mfma(
    const bfu* __restrict__ A, const bfu* __restrict__ Whi,
    const bfu* __restrict__ Wlo, const float* __restrict__ bias,
    TL* __restrict__ C) {
  __shared__ char smem[64 * 512];  // 64 rows x 256 bf16 (swizzled)
  const int t = threadIdx.x;
  const int w = t >> 6;   // wave 0..3
  const int l = t & 63;   // lane
  const int bm = blockIdx.x * 64;

  // ---- stage A rows [bm, bm+64): wave w stages rows [16w, 16w+16)
  {
    const int s = l & 31;        // 16B slot in row
    const int half = l >> 5;     // row parity within 1KB pair
#pragma unroll
    for (int i = 0; i < 8; ++i) {
      const int rb = w * 16 + i * 2;
      const int r = rb + half;
      const bfu* src = A + (size_t)(bm + r) * EMBD + ((s ^ (r & 7)) << 3);
      __builtin_amdgcn_global_load_lds(
          (const __attribute__((address_space(1))) unsigned int*)src,
          (__attribute__((address_space(3))) unsigned int*)(smem + rb * 512),
          16, 0, 0);
    }
  }
  __syncthreads();  // drains vmcnt before any wave reads LDS

  f32x4 acc[4][4];
#pragma unroll
  for (int mf = 0; mf < 4; ++mf)
#pragma unroll
    for (int nf = 0; nf < 4; ++nf) acc[mf][nf] = (f32x4)0.f;

  const int lr = l & 15;  // A-row / B-col / D-col within fragment
  const int g = l >> 4;   // k-group
  const int sw = (lr & 7) << 4;

  for (int ks = 0; ks < 8; ++ks) {
    const int k0 = ks * 32;
    short8v a[4], bh[4], bl_[4];
#pragma unroll
    for (int mf = 0; mf < 4; ++mf) {
      const int row = mf * 16 + lr;
      const int byte_ = row * 512 + (((k0 + 8 * g) * 2) ^ sw);
      a[mf] = *reinterpret_cast<const short8v*>(smem + byte_);
    }
#pragma unroll
    for (int nf = 0; nf < 4; ++nf) {
      const size_t off = (size_t)(w * 64 + nf * 16 + lr) * 256 + k0 + 8 * g;
      bh[nf] = *reinterpret_cast<const short8v*>(Whi + off);
      bl_[nf] = *reinterpret_cast<const short8v*>(Wlo + off);
    }
#pragma unroll
    for (int mf = 0; mf < 4; ++mf)
#pragma unroll
      for (int nf = 0; nf < 4; ++nf) {
        acc[mf][nf] = __builtin_amdgcn_mfma_f32_16x16x32_bf16(
            a[mf], bh[nf], acc[mf][nf], 0, 0, 0);
        acc[mf][nf] = __builtin_amdgcn_mfma_f32_16x16x32_bf16(
            a[mf], bl_[nf], acc[mf][nf], 0, 0, 0);
      }
  }

  // ---- epilogue: D[row = mf*16 + g*4 + r][col = w*64 + nf*16 + lr] + bias
#pragma unroll
  for (int nf = 0; nf < 4; ++nf) {
    const int col = w * 64 + nf * 16 + lr;
    const float bv = bias[col];
#pragma unroll
    for (int mf = 0; mf < 4; ++mf) {
      const int r0 = bm + mf * 16 + g * 4;
#pragma unroll
      for (int r = 0; r < 4; ++r)
        st1(C + (size_t)(r0 + r) * EMBD + col, acc[mf][nf][r] + bv);
    }
  }
}

// ---------------------------------------------------------------------------
// Fused gather + update, wave per node, CSR in-edges, accumulators in regs.
template <typename TL>
__global__ __launch_bounds__(256) void k_gather_update(
    const int* __restrict__ ei, const int* __restrict__ ea,
    const float* __restrict__ dinv, const float* __restrict__ bond,
    const TL* __restrict__ hl, const float* __restrict__ deg,
    const int* __restrict__ bcnt, const int* __restrict__ rowptr,
    const int* __restrict__ eids, const float* __restrict__ root,
    const float* __restrict__ gamma, const float* __restrict__ beta,
    const float* __restrict__ mean, const float* __restrict__ var,
    bfu* __restrict__ out, const int do_relu) {
  const int idx = blockIdx.x * 256 + threadIdx.x;
  const int n = idx >> 6;
  const int c = (idx & 63) << 2;
  const int base = rowptr[n];
  const int cnt = bcnt[n];
  const float dn = dinv[n];

  float a0 = 0.f, a1 = 0.f, a2 = 0.f, a3 = 0.f;
  for (int s = 0; s < cnt; ++s) {
    const int e = eids[base + s];
    const int row = ei[e];
    const float nm = dinv[row] * dn;
    const int i0 = ea[e * 3 + 0];
    const int i1 = ea[e * 3 + 1] + 5;
    const int i2 = ea[e * 3 + 2] + 11;
    const float4 b0 = *reinterpret_cast<const float4*>(bond + i0 * EMBD + c);
    const float4 b1 = *reinterpret_cast<const float4*>(bond + i1 * EMBD + c);
    const float4 b2 = *reinterpret_cast<const float4*>(bond + i2 * EMBD + c);
    const float4 hv = ld4(hl + (size_t)row * EMBD + c);
    a0 += nm * fmaxf(hv.x + b0.x + b1.x + b2.x, 0.f);
    a1 += nm * fmaxf(hv.y + b0.y + b1.y + b2.y, 0.f);
    a2 += nm * fmaxf(hv.z + b0.z + b1.z + b2.z, 0.f);
    a3 += nm * fmaxf(hv.w + b0.w + b1.w + b2.w, 0.f);
  }

  const float di = 1.0f / deg[n];
  const float4 hv = ld4(hl + (size_t)n * EMBD + c);
  const float4 r = *reinterpret_cast<const float4*>(root + c);
  const float4 mn = *reinterpret_cast<const float4*>(mean + c);
  const float4 g = *reinterpret_cast<const float4*>(gamma + c);
  const float4 vv = *reinterpret_cast<const float4*>(var + c);
  const float4 bt = *reinterpret_cast<const float4*>(beta + c);
  float v0 = a0 + fmaxf(hv.x + r.x, 0.f) * di;
  float v1 = a1 + fmaxf(hv.y + r.y, 0.f) * di;
  float v2 = a2 + fmaxf(hv.z + r.z, 0.f) * di;
  float v3 = a3 + fmaxf(hv.w + r.w, 0.f) * di;
  v0 = (v0 - mn.x) * (g.x / sqrtf(vv.x + 1e-5f)) + bt.x;
  v1 = (v1 - mn.y) * (g.y / sqrtf(vv.y + 1e-5f)) + bt.y;
  v2 = (v2 - mn.z) * (g.z / sqrtf(vv.z + 1e-5f)) + bt.z;
  v3 = (v3 - mn.w) * (g.w / sqrtf(vv.w + 1e-5f)) + bt.w;
  if (do_relu) {
    v0 = fmaxf(v0, 0.f); v1 = fmaxf(v1, 0.f);
    v2 = fmaxf(v2, 0.f); v3 = fmaxf(v3, 0.f);
  }
  st4(out + (size_t)n * EMBD + c, make_float4(v0, v1, v2, v3));
}

// ---------------------------------------------------------------------------
// Pool: batch sorted -> run-length accumulate, one atomic per (run, channel).
__global__ __launch_bounds__(256) void k_pool(const bfu* __restrict__ h,
                                              const int* __restrict__ batch,
                                              float* __restrict__ out) {
  const int c = threadIdx.x;
  const int n0 = blockIdx.x * 128;
  float acc = 0.f;
  int gprev = batch[n0];
  for (int i = 0; i < 128; ++i) {
    const int n = n0 + i;
    const int g = batch[n];
    if (g != gprev) {
      atomicAdd(&out[gprev * EMBD + c], acc);
      acc = 0.f;
      gprev = g;
    }
    acc += bf2f(h[(size_t)n * EMBD + c]);
  }
  atomicAdd(&out[gprev * EMBD + c], acc);
}

// ---------------------------------------------------------------------------
template <typename TL>
static void run_pipeline(const float* atom_emb, const float* bond_emb,
                         const float* W, const float* b, const float* root,
                         const float* gamma, const float* beta,
                         const float* mean, const float* var, const int* x,
                         const int* ei, const int* ea, const int* batch,
                         float* out, bfu* X, TL* Y, hipStream_t stream) {
  // graph metadata + bf16 W tables live in d_out (4 MiB) until the final pool
  float* deg = out;                        // NN f32
  float* dnv = out + NN;                   // NN f32
  int* bcnt = (int*)(out + 2 * NN);        // NN
  int* rowptr = bcnt + NN;                 // NN
  int* ticket = rowptr + NN;               // NN  (dead after k_scatter)
  int* bsum = ticket + NN;                 // 512
  int* eids = bsum + 512;                  // NE
  bfu* Whi = (bfu*)ticket;                 // 3*64K bfu = 384 KB <= 512 KB
  bfu* Wlo = (bfu*)(eids + NE);            // ends at 3.89 MB <= 4 MB

  k_zero<<<1024, 256, 0, stream>>>((float4*)out, (5 * NN + 512) / 4);
  k_atom_encode<<<NN / 4, 256, 0, stream>>>(atom_emb, x, X);
  k_count<<<NE / 256, 256, 0, stream>>>(ei, deg, bcnt);
  k_bsum<<<NN / 256, 256, 0, stream>>>(bcnt, bsum);
  k_bscan<<<1, 512, 0, stream>>>(bsum);
  k_rowptr<<<NN / 256, 256, 0, stream>>>(bcnt, bsum, rowptr);
  k_scatter<<<NE / 256, 256, 0, stream>>>(ei, rowptr, ticket, eids);
  k_finish_deg<<<NN / 256, 256, 0, stream>>>(deg, dnv);
  k_wt<<<3 * 256 * 256 / 256, 256, 0, stream>>>(W, Whi, Wlo);  // ticket dead now

  for (int l = 0; l < 3; ++l) {
    k_gemm_mfma<TL><<<NN / 64, 256, 0, stream>>>(
        X, Whi + l * 65536, Wlo + l * 65536, b + l * EMBD, Y);
    k_gather_update<TL><<<NN / 4, 256, 0, stream>>>(
        ei, ea, dnv, bond_emb + l * 13 * EMBD, Y, deg, bcnt, rowptr, eids,
        root + l * EMBD, gamma + l * EMBD, beta + l * EMBD, mean + l * EMBD,
        var + l * EMBD, X, (l < 2) ? 1 : 0);
  }
  // metadata now dead: zero the full output, then pool h3 (in X) into it
  k_zero<<<1024, 256, 0, stream>>>((float4*)out, NG * EMBD / 4);
  k_pool<<<NN / 128, 256, 0, stream>>>(X, batch, out);
}

extern "C" void kernel_launch(void* const* d_in, const int* in_sizes, int n_in,
                              void* d_out, int out_size, void* d_ws,
                              size_t ws_size, hipStream_t stream) {
  const float* atom_emb = (const float*)d_in[0];
  const float* bond_emb = (const float*)d_in[1];
  const float* W = (const float*)d_in[2];
  const float* b = (const float*)d_in[3];
  const float* root = (const float*)d_in[4];
  const float* gamma = (const float*)d_in[5];
  const float* beta = (const float*)d_in[6];
  const float* mean = (const float*)d_in[7];
  const float* var = (const float*)d_in[8];
  const int* x = (const int*)d_in[9];
  const int* ei = (const int*)d_in[10];
  const int* ea = (const int*)d_in[11];
  const int* batch = (const int*)d_in[12];
  float* out = (float*)d_out;

  const size_t H = (size_t)NN * EMBD;  // elements per h buffer
  char* ws = (char*)d_ws;

  if (ws_size >= H * sizeof(bfu) + H * sizeof(float)) {
    // Tier B: bf16 h, f32 hl (201 MB) — confirmed active on HW (absmax 0.031)
    bfu* X = (bfu*)ws;
    float* Y = (float*)(ws + H * sizeof(bfu));
    run_pipeline<float>(atom_emb, bond_emb, W, b, root, gamma, beta, mean,
                        var, x, ei, ea, batch, out, X, Y, stream);
  } else if (ws_size >= 2 * H * sizeof(bfu)) {
    // Tier C: bf16 both (134 MB)
    bfu* X = (bfu*)ws;
    bfu* Y = X + H;
    run_pipeline<bfu>(atom_emb, bond_emb, W, b, root, gamma, beta, mean, var,
                      x, ei, ea, batch, out, X, Y, stream);
  } else {
    k_zero<<<1024, 256, 0, stream>>>((float4*)out, NG * EMBD / 4);
  }
}

// Round 8
// 711.073 us; speedup vs baseline: 1.5767x; 1.0513x over previous
//
#include <hip/hip_runtime.h>

#define NN 131072   // nodes
#define NE 262144   // edges
#define NG 4096     // graphs
#define EMBD 256

typedef unsigned short bfu;  // raw bf16 bits (storage only; compute f32)
typedef __attribute__((ext_vector_type(8))) short short8v;   // MFMA A/B frag
typedef __attribute__((ext_vector_type(4))) float f32x4;     // MFMA C/D frag

__device__ __forceinline__ float bf2f(bfu u) {
  return __uint_as_float(((unsigned)u) << 16);
}
__device__ __forceinline__ bfu f2bf(float f) {  // round-to-nearest-even
  unsigned u = __float_as_uint(f);
  u += 0x7FFF + ((u >> 16) & 1);
  return (bfu)(u >> 16);
}
__device__ __forceinline__ float4 ld4(const float* p) {
  return *reinterpret_cast<const float4*>(p);
}
__device__ __forceinline__ float4 ld4(const bfu* p) {
  ushort4 u = *reinterpret_cast<const ushort4*>(p);
  return make_float4(bf2f(u.x), bf2f(u.y), bf2f(u.z), bf2f(u.w));
}
__device__ __forceinline__ void st4(float* p, float4 v) {
  *reinterpret_cast<float4*>(p) = v;
}
__device__ __forceinline__ void st4(bfu* p, float4 v) {
  *reinterpret_cast<ushort4*>(p) =
      make_ushort4(f2bf(v.x), f2bf(v.y), f2bf(v.z), f2bf(v.w));
}
__device__ __forceinline__ void st1(float* p, float v) { *p = v; }
__device__ __forceinline__ void st1(bfu* p, float v) { *p = f2bf(v); }

// ---------------------------------------------------------------------------
__global__ __launch_bounds__(256) void k_zero(float4* p, int n4) {
  for (int i = blockIdx.x * 256 + threadIdx.x; i < n4; i += gridDim.x * 256)
    p[i] = make_float4(0.f, 0.f, 0.f, 0.f);
}

// ---------------------------------------------------------------------------
// Atom encoder: h[n][c] = sum_f atom_emb[x[n][f] + off[f]][c]. Wave = node.
__global__ __launch_bounds__(256) void k_atom_encode(
    const float* __restrict__ atom_emb, const int* __restrict__ x,
    bfu* __restrict__ h) {
  const int idx = blockIdx.x * 256 + threadIdx.x;
  const int n = idx >> 6;
  const int c = (idx & 63) << 2;
  const int off[9] = {0, 119, 123, 135, 147, 157, 163, 168, 170};
  const int* xr = x + n * 9;
  float4 acc = make_float4(0.f, 0.f, 0.f, 0.f);
#pragma unroll
  for (int f = 0; f < 9; ++f) {
    const float4 v =
        *reinterpret_cast<const float4*>(atom_emb + (xr[f] + off[f]) * EMBD + c);
    acc.x += v.x; acc.y += v.y; acc.z += v.z; acc.w += v.w;
  }
  st4(h + (size_t)n * EMBD + c, acc);
}

// ---------------------------------------------------------------------------
// CSR build over destinations + source-degree count.
__global__ __launch_bounds__(256) void k_count(const int* __restrict__ ei,
                                               float* __restrict__ deg,
                                               int* __restrict__ bcnt) {
  const int e = blockIdx.x * 256 + threadIdx.x;
  if (e >= NE) return;
  atomicAdd(&deg[ei[e]], 1.0f);
  atomicAdd(&bcnt[ei[NE + e]], 1);
}

__global__ __launch_bounds__(256) void k_bsum(const int* __restrict__ bcnt,
                                              int* __restrict__ bsum) {
  __shared__ int s[256];
  const int t = threadIdx.x;
  s[t] = bcnt[blockIdx.x * 256 + t];
  __syncthreads();
  for (int o = 128; o; o >>= 1) {
    if (t < o) s[t] += s[t + o];
    __syncthreads();
  }
  if (t == 0) bsum[blockIdx.x] = s[0];
}

__global__ __launch_bounds__(512) void k_bscan(int* __restrict__ bsum) {
  __shared__ int s[512];
  const int t = threadIdx.x;
  s[t] = bsum[t];
  __syncthreads();
  for (int o = 1; o < 512; o <<= 1) {
    const int v = (t >= o) ? s[t - o] : 0;
    __syncthreads();
    s[t] += v;
    __syncthreads();
  }
  bsum[t] = t ? s[t - 1] : 0;  // exclusive
}

__global__ __launch_bounds__(256) void k_rowptr(const int* __restrict__ bcnt,
                                                const int* __restrict__ bsum,
                                                int* __restrict__ rowptr) {
  __shared__ int s[256];
  const int t = threadIdx.x;
  const int n = blockIdx.x * 256 + t;
  s[t] = bcnt[n];
  __syncthreads();
  for (int o = 1; o < 256; o <<= 1) {
    const int v = (t >= o) ? s[t - o] : 0;
    __syncthreads();
    s[t] += v;
    __syncthreads();
  }
  rowptr[n] = bsum[blockIdx.x] + (t ? s[t - 1] : 0);
}

__global__ __launch_bounds__(256) void k_scatter(const int* __restrict__ ei,
                                                 const int* __restrict__ rowptr,
                                                 int* __restrict__ ticket,
                                                 int* __restrict__ eids) {
  const int e = blockIdx.x * 256 + threadIdx.x;
  if (e >= NE) return;
  const int col = ei[NE + e];
  const int slot = atomicAdd(&ticket[col], 1);
  eids[rowptr[col] + slot] = e;
}

__global__ __launch_bounds__(256) void k_finish_deg(float* __restrict__ deg,
                                                    float* __restrict__ dinv) {
  const int n = blockIdx.x * 256 + threadIdx.x;
  const float d = deg[n] + 1.0f;
  deg[n] = d;
  dinv[n] = 1.0f / sqrtf(d);
}

// ---------------------------------------------------------------------------
// W split-transpose: Whi[l][n][k] = bf16(W[l][k][n]); Wlo = bf16(residual).
// Whi+Wlo represents W to ~2^-17 rel: GEMM precision == f32-W with bf16-A.
__global__ __launch_bounds__(256) void k_wt(const float* __restrict__ W,
                                            bfu* __restrict__ Whi,
                                            bfu* __restrict__ Wlo) {
  const int idx = blockIdx.x * 256 + threadIdx.x;  // (l,k,n), n fastest
  if (idx >= 3 * 256 * 256) return;
  const int n = idx & 255;
  const int k = (idx >> 8) & 255;
  const int l = idx >> 16;
  const float w = W[idx];
  const bfu hi = f2bf(w);
  const bfu lo = f2bf(w - bf2f(hi));
  const int o = ((l * 256 + n) << 8) + k;
  Whi[o] = hi;
  Wlo[o] = lo;
}

// ---------------------------------------------------------------------------
// bf16 MFMA GEMM: C[M,256] = A[M,256] @ W + bias, W = Whi + Wlo (split bf16).
// Block: 64 rows x all 256 cols, 4 waves (wave w owns cols [64w,64w+64)).
// A staged once to LDS via global_load_lds (inverse-swizzled source, rule 21);
// ds_read_b128 with byte ^= (row&7)<<4 kills the stride-512 bank conflict.
// B frags read straight from L2-hot Whi/Wlo (768 KB). No K-loop barriers.
template <typename TL>
__global__ __launch_bounds__(256) void k_gemm_mfma(
    const bfu* __restrict__ A, const bfu* __restrict__ Whi,
    const bfu* __restrict__ Wlo, const float* __restrict__ bias,
    TL* __restrict__ C) {
  __shared__ char smem[64 * 512];  // 64 rows x 256 bf16 (swizzled)
  const int t = threadIdx.x;
  const int w = t >> 6;   // wave 0..3
  const int l = t & 63;   // lane
  const int bm = blockIdx.x * 64;

  // ---- stage A rows [bm, bm+64): wave w stages rows [16w, 16w+16)
  {
    const int s = l & 31;        // 16B slot in row
    const int half = l >> 5;     // row parity within 1KB pair
#pragma unroll
    for (int i = 0; i < 8; ++i) {
      const int rb = w * 16 + i * 2;
      const int r = rb + half;
      const bfu* src = A + (size_t)(bm + r) * EMBD + ((s ^ (r & 7)) << 3);
      __builtin_amdgcn_global_load_lds(
          (const __attribute__((address_space(1))) unsigned int*)src,
          (__attribute__((address_space(3))) unsigned int*)(smem + rb * 512),
          16, 0, 0);
    }
  }
  __syncthreads();  // drains vmcnt before any wave reads LDS

  f32x4 acc[4][4];
#pragma unroll
  for (int mf = 0; mf < 4; ++mf)
#pragma unroll
    for (int nf = 0; nf < 4; ++nf) acc[mf][nf] = (f32x4)0.f;

  const int lr = l & 15;  // A-row / B-col / D-col within fragment
  const int g = l >> 4;   // k-group
  const int sw = (lr & 7) << 4;

  for (int ks = 0; ks < 8; ++ks) {
    const int k0 = ks * 32;
    short8v a[4], bh[4], bl_[4];
#pragma unroll
    for (int mf = 0; mf < 4; ++mf) {
      const int row = mf * 16 + lr;
      const int byte_ = row * 512 + (((k0 + 8 * g) * 2) ^ sw);
      a[mf] = *reinterpret_cast<const short8v*>(smem + byte_);
    }
#pragma unroll
    for (int nf = 0; nf < 4; ++nf) {
      const size_t off = (size_t)(w * 64 + nf * 16 + lr) * 256 + k0 + 8 * g;
      bh[nf] = *reinterpret_cast<const short8v*>(Whi + off);
      bl_[nf] = *reinterpret_cast<const short8v*>(Wlo + off);
    }
#pragma unroll
    for (int mf = 0; mf < 4; ++mf)
#pragma unroll
      for (int nf = 0; nf < 4; ++nf) {
        acc[mf][nf] = __builtin_amdgcn_mfma_f32_16x16x32_bf16(
            a[mf], bh[nf], acc[mf][nf], 0, 0, 0);
        acc[mf][nf] = __builtin_amdgcn_mfma_f32_16x16x32_bf16(
            a[mf], bl_[nf], acc[mf][nf], 0, 0, 0);
      }
  }

  // ---- epilogue: D[row = mf*16 + g*4 + r][col = w*64 + nf*16 + lr] + bias
#pragma unroll
  for (int nf = 0; nf < 4; ++nf) {
    const int col = w * 64 + nf * 16 + lr;
    const float bv = bias[col];
#pragma unroll
    for (int mf = 0; mf < 4; ++mf) {
      const int r0 = bm + mf * 16 + g * 4;
#pragma unroll
      for (int r = 0; r < 4; ++r)
        st1(C + (size_t)(r0 + r) * EMBD + col, acc[mf][nf][r] + bv);
    }
  }
}

// ---------------------------------------------------------------------------
// Fused gather + update, wave per node, CSR in-edges, accumulators in regs.
template <typename TL>
__global__ __launch_bounds__(256) void k_gather_update(
    const int* __restrict__ ei, const int* __restrict__ ea,
    const float* __restrict__ dinv, const float* __restrict__ bond,
    const TL* __restrict__ hl, const float* __restrict__ deg,
    const int* __restrict__ bcnt, const int* __restrict__ rowptr,
    const int* __restrict__ eids, const float* __restrict__ root,
    const float* __restrict__ gamma, const float* __restrict__ beta,
    const float* __restrict__ mean, const float* __restrict__ var,
    bfu* __restrict__ out, const int do_relu) {
  const int idx = blockIdx.x * 256 + threadIdx.x;
  const int n = idx >> 6;
  const int c = (idx & 63) << 2;
  const int base = rowptr[n];
  const int cnt = bcnt[n];
  const float dn = dinv[n];

  float a0 = 0.f, a1 = 0.f, a2 = 0.f, a3 = 0.f;
  for (int s = 0; s < cnt; ++s) {
    const int e = eids[base + s];
    const int row = ei[e];
    const float nm = dinv[row] * dn;
    const int i0 = ea[e * 3 + 0];
    const int i1 = ea[e * 3 + 1] + 5;
    const int i2 = ea[e * 3 + 2] + 11;
    const float4 b0 = *reinterpret_cast<const float4*>(bond + i0 * EMBD + c);
    const float4 b1 = *reinterpret_cast<const float4*>(bond + i1 * EMBD + c);
    const float4 b2 = *reinterpret_cast<const float4*>(bond + i2 * EMBD + c);
    const float4 hv = ld4(hl + (size_t)row * EMBD + c);
    a0 += nm * fmaxf(hv.x + b0.x + b1.x + b2.x, 0.f);
    a1 += nm * fmaxf(hv.y + b0.y + b1.y + b2.y, 0.f);
    a2 += nm * fmaxf(hv.z + b0.z + b1.z + b2.z, 0.f);
    a3 += nm * fmaxf(hv.w + b0.w + b1.w + b2.w, 0.f);
  }

  const float di = 1.0f / deg[n];
  const float4 hv = ld4(hl + (size_t)n * EMBD + c);
  const float4 r = *reinterpret_cast<const float4*>(root + c);
  const float4 mn = *reinterpret_cast<const float4*>(mean + c);
  const float4 g = *reinterpret_cast<const float4*>(gamma + c);
  const float4 vv = *reinterpret_cast<const float4*>(var + c);
  const float4 bt = *reinterpret_cast<const float4*>(beta + c);
  float v0 = a0 + fmaxf(hv.x + r.x, 0.f) * di;
  float v1 = a1 + fmaxf(hv.y + r.y, 0.f) * di;
  float v2 = a2 + fmaxf(hv.z + r.z, 0.f) * di;
  float v3 = a3 + fmaxf(hv.w + r.w, 0.f) * di;
  v0 = (v0 - mn.x) * (g.x / sqrtf(vv.x + 1e-5f)) + bt.x;
  v1 = (v1 - mn.y) * (g.y / sqrtf(vv.y + 1e-5f)) + bt.y;
  v2 = (v2 - mn.z) * (g.z / sqrtf(vv.z + 1e-5f)) + bt.z;
  v3 = (v3 - mn.w) * (g.w / sqrtf(vv.w + 1e-5f)) + bt.w;
  if (do_relu) {
    v0 = fmaxf(v0, 0.f); v1 = fmaxf(v1, 0.f);
    v2 = fmaxf(v2, 0.f); v3 = fmaxf(v3, 0.f);
  }
  st4(out + (size_t)n * EMBD + c, make_float4(v0, v1, v2, v3));
}

// ---------------------------------------------------------------------------
// Pool: batch sorted -> run-length accumulate, one atomic per (run, channel).
__global__ __launch_bounds__(256) void k_pool(const bfu* __restrict__ h,
                                              const int* __restrict__ batch,
                                              float* __restrict__ out) {
  const int c = threadIdx.x;
  const int n0 = blockIdx.x * 128;
  float acc = 0.f;
  int gprev = batch[n0];
  for (int i = 0; i < 128; ++i) {
    const int n = n0 + i;
    const int g = batch[n];
    if (g != gprev) {
      atomicAdd(&out[gprev * EMBD + c], acc);
      acc = 0.f;
      gprev = g;
    }
    acc += bf2f(h[(size_t)n * EMBD + c]);
  }
  atomicAdd(&out[gprev * EMBD + c], acc);
}

// ---------------------------------------------------------------------------
template <typename TL>
static void run_pipeline(const float* atom_emb, const float* bond_emb,
                         const float* W, const float* b, const float* root,
                         const float* gamma, const float* beta,
                         const float* mean, const float* var, const int* x,
                         const int* ei, const int* ea, const int* batch,
                         float* out, bfu* X, TL* Y, hipStream_t stream) {
  // graph metadata + bf16 W tables live in d_out (4 MiB) until the final pool
  float* deg = out;                        // NN f32
  float* dnv = out + NN;                   // NN f32
  int* bcnt = (int*)(out + 2 * NN);        // NN
  int* rowptr = bcnt + NN;                 // NN
  int* ticket = rowptr + NN;               // NN  (dead after k_scatter)
  int* bsum = ticket + NN;                 // 512
  int* eids = bsum + 512;                  // NE
  bfu* Whi = (bfu*)ticket;                 // 3*64K bfu = 384 KB <= 512 KB
  bfu* Wlo = (bfu*)(eids + NE);            // ends at 3.89 MB <= 4 MB

  k_zero<<<1024, 256, 0, stream>>>((float4*)out, (5 * NN + 512) / 4);
  k_atom_encode<<<NN / 4, 256, 0, stream>>>(atom_emb, x, X);
  k_count<<<NE / 256, 256, 0, stream>>>(ei, deg, bcnt);
  k_bsum<<<NN / 256, 256, 0, stream>>>(bcnt, bsum);
  k_bscan<<<1, 512, 0, stream>>>(bsum);
  k_rowptr<<<NN / 256, 256, 0, stream>>>(bcnt, bsum, rowptr);
  k_scatter<<<NE / 256, 256, 0, stream>>>(ei, rowptr, ticket, eids);
  k_finish_deg<<<NN / 256, 256, 0, stream>>>(deg, dnv);
  k_wt<<<3 * 256 * 256 / 256, 256, 0, stream>>>(W, Whi, Wlo);  // ticket dead now

  for (int l = 0; l < 3; ++l) {
    k_gemm_mfma<TL><<<NN / 64, 256, 0, stream>>>(
        X, Whi + l * 65536, Wlo + l * 65536, b + l * EMBD, Y);
    k_gather_update<TL><<<NN / 4, 256, 0, stream>>>(
        ei, ea, dnv, bond_emb + l * 13 * EMBD, Y, deg, bcnt, rowptr, eids,
        root + l * EMBD, gamma + l * EMBD, beta + l * EMBD, mean + l * EMBD,
        var + l * EMBD, X, (l < 2) ? 1 : 0);
  }
  // metadata now dead: zero the full output, then pool h3 (in X) into it
  k_zero<<<1024, 256, 0, stream>>>((float4*)out, NG * EMBD / 4);
  k_pool<<<NN / 128, 256, 0, stream>>>(X, batch, out);
}

extern "C" void kernel_launch(void* const* d_in, const int* in_sizes, int n_in,
                              void* d_out, int out_size, void* d_ws,
                              size_t ws_size, hipStream_t stream) {
  const float* atom_emb = (const float*)d_in[0];
  const float* bond_emb = (const float*)d_in[1];
  const float* W = (const float*)d_in[2];
  const float* b = (const float*)d_in[3];
  const float* root = (const float*)d_in[4];
  const float* gamma = (const float*)d_in[5];
  const float* beta = (const float*)d_in[6];
  const float* mean = (const float*)d_in[7];
  const float* var = (const float*)d_in[8];
  const int* x = (const int*)d_in[9];
  const int* ei = (const int*)d_in[10];
  const int* ea = (const int*)d_in[11];
  const int* batch = (const int*)d_in[12];
  float* out = (float*)d_out;

  const size_t H = (size_t)NN * EMBD;  // elements per h buffer
  char* ws = (char*)d_ws;

  // Tier C: bf16 h AND bf16 hl (134 MB). Keeps the full gather working set
  // (hl 67 MB + X 2x67 MB + metadata) under the 256 MB L3 -> no thrash.
  // Round-7 measured: f32 hl put the working set at ~273 MB > L3, causing
  // 242 MB/layer HBM fetch in k_gather_update.
  if (ws_size >= 2 * H * sizeof(bfu)) {
    bfu* X = (bfu*)ws;
    bfu* Y = X + H;
    run_pipeline<bfu>(atom_emb, bond_emb, W, b, root, gamma, beta, mean, var,
                      x, ei, ea, batch, out, X, Y, stream);
  } else {
    // ws too small for any layout: emit zeros (fails validation cleanly)
    k_zero<<<1024, 256, 0, stream>>>((float4*)out, NG * EMBD / 4);
  }
}

// Round 9
// 646.700 us; speedup vs baseline: 1.7337x; 1.0995x over previous
//
#include <hip/hip_runtime.h>

#define NN 131072   // nodes
#define NE 262144   // edges
#define NG 4096     // graphs
#define EMBD 256

typedef unsigned short bfu;  // raw bf16 bits (storage only; compute f32)
typedef __attribute__((ext_vector_type(8))) short short8v;   // MFMA A/B frag
typedef __attribute__((ext_vector_type(4))) float f32x4;     // MFMA C/D frag

__device__ __forceinline__ float bf2f(bfu u) {
  return __uint_as_float(((unsigned)u) << 16);
}
__device__ __forceinline__ bfu f2bf(float f) {  // round-to-nearest-even
  unsigned u = __float_as_uint(f);
  u += 0x7FFF + ((u >> 16) & 1);
  return (bfu)(u >> 16);
}
__device__ __forceinline__ float4 ld4(const float* p) {
  return *reinterpret_cast<const float4*>(p);
}
__device__ __forceinline__ float4 ld4(const bfu* p) {
  ushort4 u = *reinterpret_cast<const ushort4*>(p);
  return make_float4(bf2f(u.x), bf2f(u.y), bf2f(u.z), bf2f(u.w));
}
__device__ __forceinline__ void st4(float* p, float4 v) {
  *reinterpret_cast<float4*>(p) = v;
}
__device__ __forceinline__ void st4(bfu* p, float4 v) {
  *reinterpret_cast<ushort4*>(p) =
      make_ushort4(f2bf(v.x), f2bf(v.y), f2bf(v.z), f2bf(v.w));
}
__device__ __forceinline__ void st1(float* p, float v) { *p = v; }
__device__ __forceinline__ void st1(bfu* p, float v) { *p = f2bf(v); }

// ---------------------------------------------------------------------------
__global__ __launch_bounds__(256) void k_zero(float4* p, int n4) {
  for (int i = blockIdx.x * 256 + threadIdx.x; i < n4; i += gridDim.x * 256)
    p[i] = make_float4(0.f, 0.f, 0.f, 0.f);
}

// ---------------------------------------------------------------------------
// Atom encoder: h[n][c] = sum_f atom_emb[x[n][f] + off[f]][c]. Wave = node.
__global__ __launch_bounds__(256) void k_atom_encode(
    const float* __restrict__ atom_emb, const int* __restrict__ x,
    bfu* __restrict__ h) {
  const int idx = blockIdx.x * 256 + threadIdx.x;
  const int n = idx >> 6;
  const int c = (idx & 63) << 2;
  const int off[9] = {0, 119, 123, 135, 147, 157, 163, 168, 170};
  const int* xr = x + n * 9;
  float4 acc = make_float4(0.f, 0.f, 0.f, 0.f);
#pragma unroll
  for (int f = 0; f < 9; ++f) {
    const float4 v =
        *reinterpret_cast<const float4*>(atom_emb + (xr[f] + off[f]) * EMBD + c);
    acc.x += v.x; acc.y += v.y; acc.z += v.z; acc.w += v.w;
  }
  st4(h + (size_t)n * EMBD + c, acc);
}

// ---------------------------------------------------------------------------
// CSR build over destinations + source-degree count.
__global__ __launch_bounds__(256) void k_count(const int* __restrict__ ei,
                                               float* __restrict__ deg,
                                               int* __restrict__ bcnt) {
  const int e = blockIdx.x * 256 + threadIdx.x;
  if (e >= NE) return;
  atomicAdd(&deg[ei[e]], 1.0f);
  atomicAdd(&bcnt[ei[NE + e]], 1);
}

__global__ __launch_bounds__(256) void k_bsum(const int* __restrict__ bcnt,
                                              int* __restrict__ bsum) {
  __shared__ int s[256];
  const int t = threadIdx.x;
  s[t] = bcnt[blockIdx.x * 256 + t];
  __syncthreads();
  for (int o = 128; o; o >>= 1) {
    if (t < o) s[t] += s[t + o];
    __syncthreads();
  }
  if (t == 0) bsum[blockIdx.x] = s[0];
}

__global__ __launch_bounds__(512) void k_bscan(int* __restrict__ bsum) {
  __shared__ int s[512];
  const int t = threadIdx.x;
  s[t] = bsum[t];
  __syncthreads();
  for (int o = 1; o < 512; o <<= 1) {
    const int v = (t >= o) ? s[t - o] : 0;
    __syncthreads();
    s[t] += v;
    __syncthreads();
  }
  bsum[t] = t ? s[t - 1] : 0;  // exclusive
}

__global__ __launch_bounds__(256) void k_rowptr(const int* __restrict__ bcnt,
                                                const int* __restrict__ bsum,
                                                int* __restrict__ rowptr) {
  __shared__ int s[256];
  const int t = threadIdx.x;
  const int n = blockIdx.x * 256 + t;
  s[t] = bcnt[n];
  __syncthreads();
  for (int o = 1; o < 256; o <<= 1) {
    const int v = (t >= o) ? s[t - o] : 0;
    __syncthreads();
    s[t] += v;
    __syncthreads();
  }
  rowptr[n] = bsum[blockIdx.x] + (t ? s[t - 1] : 0);
}

__global__ __launch_bounds__(256) void k_finish_deg(float* __restrict__ deg,
                                                    float* __restrict__ dinv) {
  const int n = blockIdx.x * 256 + threadIdx.x;
  const float d = deg[n] + 1.0f;
  deg[n] = d;
  dinv[n] = 1.0f / sqrtf(d);
}

// ---------------------------------------------------------------------------
// Scatter edges into CSR slots as packed records {row, combo, norm} (16 B).
// row/combo/norm are layer-invariant -> computed once here, not per layer.
__global__ __launch_bounds__(256) void k_scatter(const int* __restrict__ ei,
                                                 const int* __restrict__ ea,
                                                 const float* __restrict__ dinv,
                                                 const int* __restrict__ rowptr,
                                                 int* __restrict__ ticket,
                                                 int4* __restrict__ recs) {
  const int e = blockIdx.x * 256 + threadIdx.x;
  if (e >= NE) return;
  const int row = ei[e];
  const int col = ei[NE + e];
  const int slot = atomicAdd(&ticket[col], 1);
  const int combo = ea[e * 3] * 12 + ea[e * 3 + 1] * 2 + ea[e * 3 + 2];
  const float nm = dinv[row] * dinv[col];
  recs[rowptr[col] + slot] =
      make_int4(row, combo, __float_as_int(nm), 0);
}

// ---------------------------------------------------------------------------
// Pre-sum the 60 possible bond-embedding combinations per layer:
// combo[l][cmb][c] = bond[l][a0] + bond[l][5+a1] + bond[l][11+a2],
// cmb = a0*12 + a1*2 + a2. 3*60*256 f32 = 184 KB (L1/L2-hot in gather).
__global__ __launch_bounds__(256) void k_combo(const float* __restrict__ bond,
                                               float* __restrict__ combo) {
  const int idx = blockIdx.x * 256 + threadIdx.x;  // (l, cmb, lane)
  if (idx >= 3 * 60 * 64) return;
  const int c = (idx & 63) << 2;
  const int cmb = (idx >> 6) % 60;
  const int l = idx / (60 * 64);
  const int a0 = cmb / 12, a1 = (cmb % 12) / 2, a2 = cmb & 1;
  const float* bl = bond + l * 13 * EMBD;
  const float4 b0 = ld4(bl + a0 * EMBD + c);
  const float4 b1 = ld4(bl + (5 + a1) * EMBD + c);
  const float4 b2 = ld4(bl + (11 + a2) * EMBD + c);
  st4(combo + ((size_t)(l * 60 + cmb)) * EMBD + c,
      make_float4(b0.x + b1.x + b2.x, b0.y + b1.y + b2.y,
                  b0.z + b1.z + b2.z, b0.w + b1.w + b2.w));
}

// ---------------------------------------------------------------------------
// W split-transpose: Whi[l][n][k] = bf16(W[l][k][n]); Wlo = bf16(residual).
__global__ __launch_bounds__(256) void k_wt(const float* __restrict__ W,
                                            bfu* __restrict__ Whi,
                                            bfu* __restrict__ Wlo) {
  const int idx = blockIdx.x * 256 + threadIdx.x;  // (l,k,n), n fastest
  if (idx >= 3 * 256 * 256) return;
  const int n = idx & 255;
  const int k = (idx >> 8) & 255;
  const int l = idx >> 16;
  const float w = W[idx];
  const bfu hi = f2bf(w);
  const bfu lo = f2bf(w - bf2f(hi));
  const int o = ((l * 256 + n) << 8) + k;
  Whi[o] = hi;
  Wlo[o] = lo;
}

// ---------------------------------------------------------------------------
// bf16 MFMA GEMM: C[M,256] = A[M,256] @ W + bias, W = Whi + Wlo (split bf16).
template <typename TL>
__global__ __launch_bounds__(256) void k_gemm_mfma(
    const bfu* __restrict__ A, const bfu* __restrict__ Whi,
    const bfu* __restrict__ Wlo, const float* __restrict__ bias,
    TL* __restrict__ C) {
  __shared__ char smem[64 * 512];  // 64 rows x 256 bf16 (swizzled)
  const int t = threadIdx.x;
  const int w = t >> 6;   // wave 0..3
  const int l = t & 63;   // lane
  const int bm = blockIdx.x * 64;

  // ---- stage A rows [bm, bm+64): wave w stages rows [16w, 16w+16)
  {
    const int s = l & 31;        // 16B slot in row
    const int half = l >> 5;     // row parity within 1KB pair
#pragma unroll
    for (int i = 0; i < 8; ++i) {
      const int rb = w * 16 + i * 2;
      const int r = rb + half;
      const bfu* src = A + (size_t)(bm + r) * EMBD + ((s ^ (r & 7)) << 3);
      __builtin_amdgcn_global_load_lds(
          (const __attribute__((address_space(1))) unsigned int*)src,
          (__attribute__((address_space(3))) unsigned int*)(smem + rb * 512),
          16, 0, 0);
    }
  }
  __syncthreads();  // drains vmcnt before any wave reads LDS

  f32x4 acc[4][4];
#pragma unroll
  for (int mf = 0; mf < 4; ++mf)
#pragma unroll
    for (int nf = 0; nf < 4; ++nf) acc[mf][nf] = (f32x4)0.f;

  const int lr = l & 15;  // A-row / B-col / D-col within fragment
  const int g = l >> 4;   // k-group
  const int sw = (lr & 7) << 4;

  for (int ks = 0; ks < 8; ++ks) {
    const int k0 = ks * 32;
    short8v a[4], bh[4], bl_[4];
#pragma unroll
    for (int mf = 0; mf < 4; ++mf) {
      const int row = mf * 16 + lr;
      const int byte_ = row * 512 + (((k0 + 8 * g) * 2) ^ sw);
      a[mf] = *reinterpret_cast<const short8v*>(smem + byte_);
    }
#pragma unroll
    for (int nf = 0; nf < 4; ++nf) {
      const size_t off = (size_t)(w * 64 + nf * 16 + lr) * 256 + k0 + 8 * g;
      bh[nf] = *reinterpret_cast<const short8v*>(Whi + off);
      bl_[nf] = *reinterpret_cast<const short8v*>(Wlo + off);
    }
#pragma unroll
    for (int mf = 0; mf < 4; ++mf)
#pragma unroll
      for (int nf = 0; nf < 4; ++nf) {
        acc[mf][nf] = __builtin_amdgcn_mfma_f32_16x16x32_bf16(
            a[mf], bh[nf], acc[mf][nf], 0, 0, 0);
        acc[mf][nf] = __builtin_amdgcn_mfma_f32_16x16x32_bf16(
            a[mf], bl_[nf], acc[mf][nf], 0, 0, 0);
      }
  }

  // ---- epilogue: D[row = mf*16 + g*4 + r][col = w*64 + nf*16 + lr] + bias
#pragma unroll
  for (int nf = 0; nf < 4; ++nf) {
    const int col = w * 64 + nf * 16 + lr;
    const float bv = bias[col];
#pragma unroll
    for (int mf = 0; mf < 4; ++mf) {
      const int r0 = bm + mf * 16 + g * 4;
#pragma unroll
      for (int r = 0; r < 4; ++r)
        st1(C + (size_t)(r0 + r) * EMBD + col, acc[mf][nf][r] + bv);
    }
  }
}

// ---------------------------------------------------------------------------
// Fused gather + update, wave per node. Per edge: one uniform 16B rec load,
// then two independent loads (combo table, hl gather). No ei/ea/dinv/bond
// traffic, no 3x bond loads — round-8 PMC showed VALU-issue-bound (64% busy,
// 26% HBM), so the win is cutting per-edge instruction count.
template <typename TL>
__global__ __launch_bounds__(256) void k_gather_update(
    const int4* __restrict__ recs, const float* __restrict__ combo,
    const TL* __restrict__ hl, const float* __restrict__ deg,
    const int* __restrict__ bcnt, const int* __restrict__ rowptr,
    const float* __restrict__ root, const float* __restrict__ gamma,
    const float* __restrict__ beta, const float* __restrict__ mean,
    const float* __restrict__ var, bfu* __restrict__ out,
    const int do_relu) {
  const int idx = blockIdx.x * 256 + threadIdx.x;
  const int n = idx >> 6;
  const int c = (idx & 63) << 2;
  const int base = rowptr[n];
  const int cnt = bcnt[n];

  float a0 = 0.f, a1 = 0.f, a2 = 0.f, a3 = 0.f;
  for (int s = 0; s < cnt; ++s) {
    const int4 rec = recs[base + s];
    const float nm = __int_as_float(rec.z);
    const float4 ee = ld4(combo + (size_t)rec.y * EMBD + c);
    const float4 hv = ld4(hl + (size_t)rec.x * EMBD + c);
    a0 += nm * fmaxf(hv.x + ee.x, 0.f);
    a1 += nm * fmaxf(hv.y + ee.y, 0.f);
    a2 += nm * fmaxf(hv.z + ee.z, 0.f);
    a3 += nm * fmaxf(hv.w + ee.w, 0.f);
  }

  const float di = 1.0f / deg[n];
  const float4 hv = ld4(hl + (size_t)n * EMBD + c);
  const float4 r = *reinterpret_cast<const float4*>(root + c);
  const float4 mn = *reinterpret_cast<const float4*>(mean + c);
  const float4 g = *reinterpret_cast<const float4*>(gamma + c);
  const float4 vv = *reinterpret_cast<const float4*>(var + c);
  const float4 bt = *reinterpret_cast<const float4*>(beta + c);
  float v0 = a0 + fmaxf(hv.x + r.x, 0.f) * di;
  float v1 = a1 + fmaxf(hv.y + r.y, 0.f) * di;
  float v2 = a2 + fmaxf(hv.z + r.z, 0.f) * di;
  float v3 = a3 + fmaxf(hv.w + r.w, 0.f) * di;
  v0 = (v0 - mn.x) * (g.x / sqrtf(vv.x + 1e-5f)) + bt.x;
  v1 = (v1 - mn.y) * (g.y / sqrtf(vv.y + 1e-5f)) + bt.y;
  v2 = (v2 - mn.z) * (g.z / sqrtf(vv.z + 1e-5f)) + bt.z;
  v3 = (v3 - mn.w) * (g.w / sqrtf(vv.w + 1e-5f)) + bt.w;
  if (do_relu) {
    v0 = fmaxf(v0, 0.f); v1 = fmaxf(v1, 0.f);
    v2 = fmaxf(v2, 0.f); v3 = fmaxf(v3, 0.f);
  }
  st4(out + (size_t)n * EMBD + c, make_float4(v0, v1, v2, v3));
}

// ---------------------------------------------------------------------------
// Pool: batch sorted -> run-length accumulate, one atomic per (run, channel).
__global__ __launch_bounds__(256) void k_pool(const bfu* __restrict__ h,
                                              const int* __restrict__ batch,
                                              float* __restrict__ out) {
  const int c = threadIdx.x;
  const int n0 = blockIdx.x * 128;
  float acc = 0.f;
  int gprev = batch[n0];
  for (int i = 0; i < 128; ++i) {
    const int n = n0 + i;
    const int g = batch[n];
    if (g != gprev) {
      atomicAdd(&out[gprev * EMBD + c], acc);
      acc = 0.f;
      gprev = g;
    }
    acc += bf2f(h[(size_t)n * EMBD + c]);
  }
  atomicAdd(&out[gprev * EMBD + c], acc);
}

// ---------------------------------------------------------------------------
extern "C" void kernel_launch(void* const* d_in, const int* in_sizes, int n_in,
                              void* d_out, int out_size, void* d_ws,
                              size_t ws_size, hipStream_t stream) {
  const float* atom_emb = (const float*)d_in[0];
  const float* bond_emb = (const float*)d_in[1];
  const float* W = (const float*)d_in[2];
  const float* b = (const float*)d_in[3];
  const float* root = (const float*)d_in[4];
  const float* gamma = (const float*)d_in[5];
  const float* beta = (const float*)d_in[6];
  const float* mean = (const float*)d_in[7];
  const float* var = (const float*)d_in[8];
  const int* x = (const int*)d_in[9];
  const int* ei = (const int*)d_in[10];
  const int* ea = (const int*)d_in[11];
  const int* batch = (const int*)d_in[12];
  float* out = (float*)d_out;

  const size_t H = (size_t)NN * EMBD;  // elements per h buffer
  // ws layout: X (bf16, 67MB) | Y (bf16, 67MB) | recs (NE int4, 4MB) |
  //            combo (3*60*256 f32, 184KB)  => 138.6 MB total
  const size_t need = 2 * H * sizeof(bfu) + (size_t)NE * 16 +
                      (size_t)3 * 60 * EMBD * sizeof(float);
  if (ws_size < need) {  // fails validation cleanly instead of faulting
    k_zero<<<1024, 256, 0, stream>>>((float4*)out, NG * EMBD / 4);
    return;
  }
  char* ws = (char*)d_ws;
  bfu* X = (bfu*)ws;
  bfu* Y = X + H;
  int4* recs = (int4*)(ws + 2 * H * sizeof(bfu));
  float* combo = (float*)(recs + NE);

  // graph metadata + bf16 W tables live in d_out (4 MiB) until the final pool
  float* deg = out;                        // NN f32
  float* dnv = out + NN;                   // NN f32
  int* bcnt = (int*)(out + 2 * NN);        // NN
  int* rowptr = bcnt + NN;                 // NN
  int* ticket = rowptr + NN;               // NN  (dead after k_scatter)
  int* bsum = ticket + NN;                 // 512
  int* eids_spc = bsum + 512;              // NE  (spacing only)
  bfu* Whi = (bfu*)ticket;                 // 384 KB <= 512 KB, after scatter
  bfu* Wlo = (bfu*)(eids_spc + NE);        // ends at 3.89 MB <= 4 MB

  k_zero<<<1024, 256, 0, stream>>>((float4*)out, (5 * NN + 512) / 4);
  k_atom_encode<<<NN / 4, 256, 0, stream>>>(atom_emb, x, X);
  k_count<<<NE / 256, 256, 0, stream>>>(ei, deg, bcnt);
  k_bsum<<<NN / 256, 256, 0, stream>>>(bcnt, bsum);
  k_bscan<<<1, 512, 0, stream>>>(bsum);
  k_rowptr<<<NN / 256, 256, 0, stream>>>(bcnt, bsum, rowptr);
  k_finish_deg<<<NN / 256, 256, 0, stream>>>(deg, dnv);   // before scatter
  k_scatter<<<NE / 256, 256, 0, stream>>>(ei, ea, dnv, rowptr, ticket, recs);
  k_wt<<<3 * 256 * 256 / 256, 256, 0, stream>>>(W, Whi, Wlo);  // ticket dead
  k_combo<<<(3 * 60 * 64 + 255) / 256, 256, 0, stream>>>(bond_emb, combo);

  for (int l = 0; l < 3; ++l) {
    k_gemm_mfma<bfu><<<NN / 64, 256, 0, stream>>>(
        X, Whi + l * 65536, Wlo + l * 65536, b + l * EMBD, Y);
    k_gather_update<bfu><<<NN / 4, 256, 0, stream>>>(
        recs, combo + (size_t)l * 60 * EMBD, Y, deg, bcnt, rowptr,
        root + l * EMBD, gamma + l * EMBD, beta + l * EMBD, mean + l * EMBD,
        var + l * EMBD, X, (l < 2) ? 1 : 0);
  }
  // metadata now dead: zero the full output, then pool h3 (in X) into it
  k_zero<<<1024, 256, 0, stream>>>((float4*)out, NG * EMBD / 4);
  k_pool<<<NN / 128, 256, 0, stream>>>(X, batch, out);
}